// Round 1
// baseline (233.280 us; speedup 1.0000x reference)
//
#include <hip/hip_runtime.h>
#include <hip/hip_bf16.h>
#include <stdint.h>

#define B_  32
#define S_  4096
#define D_  64
#define DK_ 256

typedef float f32x4 __attribute__((ext_vector_type(4)));
typedef short s16x8 __attribute__((ext_vector_type(8)));

static __device__ __forceinline__ uint16_t f2bf(float f) {
    union { float f; uint32_t u; } x; x.f = f;
    uint32_t u = x.u;
    u += 0x7FFFu + ((u >> 16) & 1u);   // RNE
    return (uint16_t)(u >> 16);
}

// ---------------------------------------------------------------------------
// Kernel 1: fp32 projection GEMMs with s-split + atomics.
// Kp_f32[b][kk][d] += sum_s E_w[kk][s] * k[b][s][d]   (proj=0)
// Vp_f32[b][kk][d] += sum_s E_w[kk][s] * v[b][s][d]   (proj=1)
// grid.x = 2 proj * 32 b * 4 kk-tiles * 8 s-splits = 2048
// ---------------------------------------------------------------------------
__global__ __launch_bounds__(256) void proj_accum(
        const float* __restrict__ kin, const float* __restrict__ vin,
        const float* __restrict__ E_w,
        float* __restrict__ Kp, float* __restrict__ Vp) {
    const int wg   = blockIdx.x;
    const int ss   = wg & 7;
    const int kkt  = (wg >> 3) & 3;
    const int b    = (wg >> 5) & 31;
    const int proj = wg >> 10;
    const float* x  = proj ? vin : kin;
    float* out      = proj ? Vp : Kp;

    __shared__ __align__(16) float Ew_s[16][68];  // [s_local][kk_local]
    __shared__ __align__(16) float X_s[16][68];   // [s_local][d]

    const int tid = threadIdx.x;
    const int ty = tid >> 4;   // 0..15 -> kk group
    const int tx = tid & 15;   // 0..15 -> d group

    float acc[4][4] = {};

    const float* xb = x + (size_t)b * S_ * D_;
    const int s_base = ss * 512;

    for (int s0 = s_base; s0 < s_base + 512; s0 += 16) {
        __syncthreads();
        {   // stage E_w tile: 64 kk x 16 s  (transposed into [s][kk])
            const int kkl = tid >> 2;
            const int su  = (tid & 3) * 4;
            const float4 ew = *(const float4*)(E_w + (size_t)(kkt*64 + kkl) * S_ + s0 + su);
            Ew_s[su+0][kkl] = ew.x; Ew_s[su+1][kkl] = ew.y;
            Ew_s[su+2][kkl] = ew.z; Ew_s[su+3][kkl] = ew.w;
        }
        {   // stage x tile: 16 s x 64 d (row-major)
            const int sl = tid >> 4;
            const int du = (tid & 15) * 4;
            *(float4*)&X_s[sl][du] = *(const float4*)(xb + (size_t)(s0 + sl) * D_ + du);
        }
        __syncthreads();
        #pragma unroll
        for (int sc = 0; sc < 16; ++sc) {
            const float4 e4 = *(const float4*)&Ew_s[sc][ty*4];
            const float4 x4 = *(const float4*)&X_s[sc][tx*4];
            const float ev[4] = {e4.x, e4.y, e4.z, e4.w};
            const float xv[4] = {x4.x, x4.y, x4.z, x4.w};
            #pragma unroll
            for (int i = 0; i < 4; ++i)
                #pragma unroll
                for (int j = 0; j < 4; ++j)
                    acc[i][j] = fmaf(ev[i], xv[j], acc[i][j]);
        }
    }

    #pragma unroll
    for (int i = 0; i < 4; ++i) {
        const int kk = kkt*64 + ty*4 + i;
        float* op = out + ((size_t)b * DK_ + kk) * D_ + tx*4;
        #pragma unroll
        for (int j = 0; j < 4; ++j) atomicAdd(op + j, acc[i][j]);
    }
}

// ---------------------------------------------------------------------------
// Kernel 1b: add bias, convert to bf16.
// Kbf[b][kk][d] (d contiguous) ; Vbf[b][d][kk] (kk contiguous)
// ---------------------------------------------------------------------------
__global__ __launch_bounds__(256) void bias_cvt(
        const float* __restrict__ Kp, const float* __restrict__ Vp,
        const float* __restrict__ E_b,
        uint16_t* __restrict__ Kbf, uint16_t* __restrict__ Vbf) {
    const int idx = blockIdx.x * 256 + threadIdx.x;   // 0 .. 524287
    const int b  = idx >> 14;
    const int r  = idx & 16383;
    const int kk = r >> 6;
    const int d  = r & 63;
    const float bias = E_b[kk];
    Kbf[idx] = f2bf(Kp[idx] + bias);
    Vbf[((b * 64 + d) << 8) + kk] = f2bf(Vp[idx] + bias);
}

// ---------------------------------------------------------------------------
// Kernel 2: fused scores -> softmax -> PV, MFMA 16x16x32 bf16.
// One wave = 16 q rows. Block = 4 waves = 64 rows. grid = 32 b * 64 = 2048.
// ---------------------------------------------------------------------------
__global__ __launch_bounds__(256) void attn(
        const float* __restrict__ q,
        const uint16_t* __restrict__ Kbf, const uint16_t* __restrict__ Vbf,
        float* __restrict__ out) {
    const int wg   = blockIdx.x;
    const int st   = wg & 63;
    const int b    = wg >> 6;
    const int wave = threadIdx.x >> 6;
    const int lane = threadIdx.x & 63;
    const int l16  = lane & 15;
    const int grp  = lane >> 4;
    const int s0   = st * 64 + wave * 16;

    __shared__ __align__(16) uint16_t P_lds[4][16][264];

    // q A-fragments (scaled by 1/sqrt(64) = 0.125 before bf16 cvt)
    s16x8 qa[2];
    {
        const float* qp = q + ((size_t)b * S_ + s0 + l16) * D_;
        #pragma unroll
        for (int kt = 0; kt < 2; ++kt) {
            const int d0 = kt*32 + grp*8;
            const float4 f0 = *(const float4*)(qp + d0);
            const float4 f1 = *(const float4*)(qp + d0 + 4);
            s16x8 a;
            a[0] = (short)f2bf(f0.x * 0.125f);
            a[1] = (short)f2bf(f0.y * 0.125f);
            a[2] = (short)f2bf(f0.z * 0.125f);
            a[3] = (short)f2bf(f0.w * 0.125f);
            a[4] = (short)f2bf(f1.x * 0.125f);
            a[5] = (short)f2bf(f1.y * 0.125f);
            a[6] = (short)f2bf(f1.z * 0.125f);
            a[7] = (short)f2bf(f1.w * 0.125f);
            qa[kt] = a;
        }
    }

    // scores: acc[nt][r] = S[row = grp*4+r][kk = nt*16 + l16]
    f32x4 acc[16];
    {
        const uint16_t* Kb = Kbf + (size_t)b * DK_ * D_;
        #pragma unroll
        for (int nt = 0; nt < 16; ++nt) {
            f32x4 c = {0.f, 0.f, 0.f, 0.f};
            #pragma unroll
            for (int kt = 0; kt < 2; ++kt) {
                const int kk = nt*16 + l16;
                const int d0 = kt*32 + grp*8;
                const s16x8 bf = *(const s16x8*)(Kb + kk * D_ + d0);
                c = __builtin_amdgcn_mfma_f32_16x16x32_bf16(qa[kt], bf, c, 0, 0, 0);
            }
            acc[nt] = c;
        }
    }

    // softmax over kk (256) for each of this lane's 4 rows
    float m[4], lsum[4];
    #pragma unroll
    for (int r = 0; r < 4; ++r) {
        float mm = acc[0][r];
        #pragma unroll
        for (int nt = 1; nt < 16; ++nt) mm = fmaxf(mm, acc[nt][r]);
        #pragma unroll
        for (int off = 1; off < 16; off <<= 1) mm = fmaxf(mm, __shfl_xor(mm, off));
        m[r] = mm;
        lsum[r] = 0.f;
    }
    #pragma unroll
    for (int nt = 0; nt < 16; ++nt) {
        #pragma unroll
        for (int r = 0; r < 4; ++r) {
            const float e = __expf(acc[nt][r] - m[r]);
            acc[nt][r] = e;
            lsum[r] += e;
        }
    }
    #pragma unroll
    for (int r = 0; r < 4; ++r) {
        #pragma unroll
        for (int off = 1; off < 16; off <<= 1) lsum[r] += __shfl_xor(lsum[r], off);
        lsum[r] = 1.f / lsum[r];
    }

    // P (normalized, bf16) -> LDS in A-layout-friendly row-major [row][kk]
    #pragma unroll
    for (int nt = 0; nt < 16; ++nt) {
        #pragma unroll
        for (int r = 0; r < 4; ++r)
            P_lds[wave][grp*4 + r][nt*16 + l16] = f2bf(acc[nt][r] * lsum[r]);
    }

    // PV: out[row][d] = sum_kk P[row][kk] * V[kk][d]
    const uint16_t* Vb = Vbf + (size_t)b * D_ * DK_;
    #pragma unroll
    for (int nt2 = 0; nt2 < 4; ++nt2) {
        f32x4 o = {0.f, 0.f, 0.f, 0.f};
        #pragma unroll
        for (int kt2 = 0; kt2 < 8; ++kt2) {
            const int kk0 = kt2*32 + grp*8;
            const s16x8 pa = *(const s16x8*)&P_lds[wave][l16][kk0];
            const s16x8 vb = *(const s16x8*)(Vb + (nt2*16 + l16) * DK_ + kk0);
            o = __builtin_amdgcn_mfma_f32_16x16x32_bf16(pa, vb, o, 0, 0, 0);
        }
        #pragma unroll
        for (int r = 0; r < 4; ++r)
            out[((size_t)b * S_ + s0 + grp*4 + r) * D_ + nt2*16 + l16] = o[r];
    }
}

extern "C" void kernel_launch(void* const* d_in, const int* in_sizes, int n_in,
                              void* d_out, int out_size, void* d_ws, size_t ws_size,
                              hipStream_t stream) {
    const float* q   = (const float*)d_in[0];
    const float* k   = (const float*)d_in[1];
    const float* v   = (const float*)d_in[2];
    const float* E_w = (const float*)d_in[3];
    const float* E_b = (const float*)d_in[4];
    float* out = (float*)d_out;

    char* ws = (char*)d_ws;
    float*    Kpf = (float*)(ws);                       // 2 MB
    float*    Vpf = (float*)(ws + (2u << 20));          // 2 MB
    uint16_t* Kbf = (uint16_t*)(ws + (4u << 20));       // 1 MB
    uint16_t* Vbf = (uint16_t*)(ws + (5u << 20));       // 1 MB

    hipMemsetAsync(ws, 0, (4u << 20), stream);
    proj_accum<<<2048, 256, 0, stream>>>(k, v, E_w, Kpf, Vpf);
    bias_cvt<<<2048, 256, 0, stream>>>(Kpf, Vpf, E_b, Kbf, Vbf);
    attn<<<2048, 256, 0, stream>>>(q, Kbf, Vbf, out);
}

// Round 3
// 161.215 us; speedup vs baseline: 1.4470x; 1.4470x over previous
//
#include <hip/hip_runtime.h>
#include <hip/hip_bf16.h>
#include <stdint.h>

#define B_  32
#define S_  4096
#define D_  64
#define DK_ 256

typedef float f32x4 __attribute__((ext_vector_type(4)));
typedef short s16x8 __attribute__((ext_vector_type(8)));
typedef short s16x4 __attribute__((ext_vector_type(4)));

static __device__ __forceinline__ uint16_t f2bf(float f) {
    union { float f; uint32_t u; } x; x.f = f;
    uint32_t u = x.u;
    u += 0x7FFFu + ((u >> 16) & 1u);   // RNE
    return (uint16_t)(u >> 16);
}

static __device__ __forceinline__ void gload_lds16(const uint16_t* g, uint16_t* l) {
    __builtin_amdgcn_global_load_lds(
        (const __attribute__((address_space(1))) uint32_t*)g,
        (__attribute__((address_space(3))) uint32_t*)l, 16, 0, 0);
}

// ---------------------------------------------------------------------------
// Pass A1: E_w fp32 -> bf16, same [DK][S] layout (s contiguous = MFMA k-contig).
// grid 512 x 256, 8 elements/thread.
// ---------------------------------------------------------------------------
__global__ __launch_bounds__(256) void ewcvt(const float* __restrict__ E_w,
                                             uint16_t* __restrict__ Ewb) {
    const int idx = (blockIdx.x * 256 + threadIdx.x) * 8;
    const float4 f0 = *(const float4*)(E_w + idx);
    const float4 f1 = *(const float4*)(E_w + idx + 4);
    s16x8 o;
    o[0] = (short)f2bf(f0.x); o[1] = (short)f2bf(f0.y);
    o[2] = (short)f2bf(f0.z); o[3] = (short)f2bf(f0.w);
    o[4] = (short)f2bf(f1.x); o[5] = (short)f2bf(f1.y);
    o[6] = (short)f2bf(f1.z); o[7] = (short)f2bf(f1.w);
    *(s16x8*)(Ewb + idx) = o;
}

// ---------------------------------------------------------------------------
// Pass A2: transpose + cvt: x[b][s][d] fp32 -> xT[b][d][s] bf16.
// grid = 2 inputs * 32 b * 64 s-tiles = 4096 blocks, 256 threads.
// 64x64 tile via LDS; both global sides fully vectorized/coalesced.
// ---------------------------------------------------------------------------
__global__ __launch_bounds__(256) void tcvt(
        const float* __restrict__ kin, const float* __restrict__ vin,
        uint16_t* __restrict__ kT, uint16_t* __restrict__ vT) {
    const int bid = blockIdx.x;
    const int st  = bid & 63;
    const int b   = (bid >> 6) & 31;
    const int inp = bid >> 11;
    const float* src = (inp ? vin : kin) + ((size_t)b * S_ + st * 64) * D_;
    uint16_t*    dst = (inp ? vT : kT) + (size_t)b * D_ * S_ + st * 64;

    __shared__ __align__(16) uint16_t T[64][72];   // [d][s_local], padded

    const int t  = threadIdx.x;
    const int ts = t >> 4;    // s sub-tile (4 rows)
    const int td = t & 15;    // d sub-tile (4 cols)

    uint16_t tmp[4][4];
    #pragma unroll
    for (int i = 0; i < 4; ++i) {
        const float4 f = *(const float4*)(src + (size_t)(ts*4 + i) * D_ + td*4);
        tmp[i][0] = f2bf(f.x); tmp[i][1] = f2bf(f.y);
        tmp[i][2] = f2bf(f.z); tmp[i][3] = f2bf(f.w);
    }
    #pragma unroll
    for (int j = 0; j < 4; ++j) {
        s16x4 v4;
        v4[0] = (short)tmp[0][j]; v4[1] = (short)tmp[1][j];
        v4[2] = (short)tmp[2][j]; v4[3] = (short)tmp[3][j];
        *(s16x4*)&T[td*4 + j][ts*4] = v4;
    }
    __syncthreads();
    #pragma unroll
    for (int i = 0; i < 2; ++i) {
        const int idx = i * 256 + t;
        const int d = idx >> 3;       // 0..63
        const int c = idx & 7;        // 16B chunk within the 128B row
        const s16x8 vv = *(const s16x8*)&T[d][c*8];
        *(s16x8*)(dst + (size_t)d * S_ + c*8) = vv;
    }
}

// ---------------------------------------------------------------------------
// Pass B: projection GEMM on MFMA.
// C[b,p][kk][d] += sum_s Ewb[kk][s] * xT[b,p][d][s],  fp32 atomics.
// grid = 2 proj * 32 b * 8 s-split = 512 blocks (2/CU), 256 threads (4 waves).
// Tile M=256 (kk) x N=64 (d), BK=32, K-loop 16.
// LDS lane-linear layout: seg = 1KB = [4 kchunk][16 row][16B]; frag read =
// seg_base + lane*16 -> conflict-free ds_read_b128; global_load_lds dest is
// wave-uniform base (HW adds lane*16), source pre-permuted per-lane.
// ---------------------------------------------------------------------------
__global__ __launch_bounds__(256) void proj_mfma(
        const uint16_t* __restrict__ Ewb,
        const uint16_t* __restrict__ kT, const uint16_t* __restrict__ vT,
        float* __restrict__ Kp, float* __restrict__ Vp) {
    const int bid = blockIdx.x;
    const int ss = bid & 7;
    const int b  = (bid >> 3) & 31;
    const int p  = bid >> 8;
    const uint16_t* xT = (p ? vT : kT) + (size_t)b * D_ * S_;
    float* outp        = (p ? Vp : Kp) + (size_t)b * DK_ * D_;

    __shared__ __align__(16) uint16_t lds[20 * 512];  // A: segs 0..15 (16KB), B: segs 16..19 (4KB)

    const int tid  = threadIdx.x;
    const int w    = tid >> 6;
    const int lane = tid & 63;
    const int l16  = lane & 15;
    const int grp  = lane >> 4;

    // per-lane global sources (advance 32 bf16 = 64B per K-step)
    const int s0 = ss * 512 + grp * 8;
    const uint16_t* srcA[4];
    #pragma unroll
    for (int i = 0; i < 4; ++i)
        srcA[i] = Ewb + (size_t)((w*4 + i)*16 + l16) * S_ + s0;
    const uint16_t* srcB = xT + (size_t)(w*16 + l16) * S_ + s0;

    f32x4 acc[4][4] = {};

    for (int t = 0; t < 16; ++t) {
        // stage: A segs w*4..w*4+3, B seg 16+w  (5 x global_load_lds width-16)
        #pragma unroll
        for (int i = 0; i < 4; ++i)
            gload_lds16(srcA[i] + t*32, &lds[(w*4 + i) * 512]);
        gload_lds16(srcB + t*32, &lds[(16 + w) * 512]);
        __syncthreads();   // compiler drains vmcnt(0) before s_barrier

        s16x8 bf[4];
        #pragma unroll
        for (int nt = 0; nt < 4; ++nt)
            bf[nt] = *(const s16x8*)&lds[(16 + nt) * 512 + lane*8];
        #pragma unroll
        for (int m = 0; m < 4; ++m) {
            const s16x8 af = *(const s16x8*)&lds[(w*4 + m) * 512 + lane*8];
            #pragma unroll
            for (int nt = 0; nt < 4; ++nt)
                acc[m][nt] = __builtin_amdgcn_mfma_f32_16x16x32_bf16(af, bf[nt], acc[m][nt], 0, 0, 0);
        }
        __syncthreads();   // LDS consumed; next iter may overwrite
    }

    // C/D layout: row = grp*4 + r (kk within m-tile), col = l16 (d)
    #pragma unroll
    for (int m = 0; m < 4; ++m)
        #pragma unroll
        for (int nt = 0; nt < 4; ++nt)
            #pragma unroll
            for (int r = 0; r < 4; ++r)
                atomicAdd(outp + (size_t)(w*64 + m*16 + grp*4 + r) * D_ + nt*16 + l16,
                          acc[m][nt][r]);
}

// ---------------------------------------------------------------------------
// bias + cvt: Kbf[b][kk][d] (d contig), Vbf[b][d][kk] (kk contig)
// ---------------------------------------------------------------------------
__global__ __launch_bounds__(256) void bias_cvt(
        const float* __restrict__ Kp, const float* __restrict__ Vp,
        const float* __restrict__ E_b,
        uint16_t* __restrict__ Kbf, uint16_t* __restrict__ Vbf) {
    const int idx = blockIdx.x * 256 + threadIdx.x;   // 0 .. 524287
    const int b  = idx >> 14;
    const int r  = idx & 16383;
    const int kk = r >> 6;
    const int d  = r & 63;
    const float bias = E_b[kk];
    Kbf[idx] = f2bf(Kp[idx] + bias);
    Vbf[((b * 64 + d) << 8) + kk] = f2bf(Vp[idx] + bias);
}

// ---------------------------------------------------------------------------
// Fused scores -> softmax -> PV, MFMA 16x16x32 bf16 (unchanged, known-correct)
// ---------------------------------------------------------------------------
__global__ __launch_bounds__(256) void attn(
        const float* __restrict__ q,
        const uint16_t* __restrict__ Kbf, const uint16_t* __restrict__ Vbf,
        float* __restrict__ out) {
    const int wg   = blockIdx.x;
    const int st   = wg & 63;
    const int b    = wg >> 6;
    const int wave = threadIdx.x >> 6;
    const int lane = threadIdx.x & 63;
    const int l16  = lane & 15;
    const int grp  = lane >> 4;
    const int s0   = st * 64 + wave * 16;

    __shared__ __align__(16) uint16_t P_lds[4][16][264];

    s16x8 qa[2];
    {
        const float* qp = q + ((size_t)b * S_ + s0 + l16) * D_;
        #pragma unroll
        for (int kt = 0; kt < 2; ++kt) {
            const int d0 = kt*32 + grp*8;
            const float4 f0 = *(const float4*)(qp + d0);
            const float4 f1 = *(const float4*)(qp + d0 + 4);
            s16x8 a;
            a[0] = (short)f2bf(f0.x * 0.125f);
            a[1] = (short)f2bf(f0.y * 0.125f);
            a[2] = (short)f2bf(f0.z * 0.125f);
            a[3] = (short)f2bf(f0.w * 0.125f);
            a[4] = (short)f2bf(f1.x * 0.125f);
            a[5] = (short)f2bf(f1.y * 0.125f);
            a[6] = (short)f2bf(f1.z * 0.125f);
            a[7] = (short)f2bf(f1.w * 0.125f);
            qa[kt] = a;
        }
    }

    f32x4 acc[16];
    {
        const uint16_t* Kb = Kbf + (size_t)b * DK_ * D_;
        #pragma unroll
        for (int nt = 0; nt < 16; ++nt) {
            f32x4 c = {0.f, 0.f, 0.f, 0.f};
            #pragma unroll
            for (int kt = 0; kt < 2; ++kt) {
                const int kk = nt*16 + l16;
                const int d0 = kt*32 + grp*8;
                const s16x8 bfv = *(const s16x8*)(Kb + kk * D_ + d0);
                c = __builtin_amdgcn_mfma_f32_16x16x32_bf16(qa[kt], bfv, c, 0, 0, 0);
            }
            acc[nt] = c;
        }
    }

    float m[4], lsum[4];
    #pragma unroll
    for (int r = 0; r < 4; ++r) {
        float mm = acc[0][r];
        #pragma unroll
        for (int nt = 1; nt < 16; ++nt) mm = fmaxf(mm, acc[nt][r]);
        #pragma unroll
        for (int off = 1; off < 16; off <<= 1) mm = fmaxf(mm, __shfl_xor(mm, off));
        m[r] = mm;
        lsum[r] = 0.f;
    }
    #pragma unroll
    for (int nt = 0; nt < 16; ++nt) {
        #pragma unroll
        for (int r = 0; r < 4; ++r) {
            const float e = __expf(acc[nt][r] - m[r]);
            acc[nt][r] = e;
            lsum[r] += e;
        }
    }
    #pragma unroll
    for (int r = 0; r < 4; ++r) {
        #pragma unroll
        for (int off = 1; off < 16; off <<= 1) lsum[r] += __shfl_xor(lsum[r], off);
        lsum[r] = 1.f / lsum[r];
    }

    #pragma unroll
    for (int nt = 0; nt < 16; ++nt) {
        #pragma unroll
        for (int r = 0; r < 4; ++r)
            P_lds[wave][grp*4 + r][nt*16 + l16] = f2bf(acc[nt][r] * lsum[r]);
    }

    const uint16_t* Vb = Vbf + (size_t)b * D_ * DK_;
    #pragma unroll
    for (int nt2 = 0; nt2 < 4; ++nt2) {
        f32x4 o = {0.f, 0.f, 0.f, 0.f};
        #pragma unroll
        for (int kt2 = 0; kt2 < 8; ++kt2) {
            const int kk0 = kt2*32 + grp*8;
            const s16x8 pa = *(const s16x8*)&P_lds[wave][l16][kk0];
            const s16x8 vb = *(const s16x8*)(Vb + (nt2*16 + l16) * DK_ + kk0);
            o = __builtin_amdgcn_mfma_f32_16x16x32_bf16(pa, vb, o, 0, 0, 0);
        }
        #pragma unroll
        for (int r = 0; r < 4; ++r)
            out[((size_t)b * S_ + s0 + grp*4 + r) * D_ + nt2*16 + l16] = o[r];
    }
}

extern "C" void kernel_launch(void* const* d_in, const int* in_sizes, int n_in,
                              void* d_out, int out_size, void* d_ws, size_t ws_size,
                              hipStream_t stream) {
    const float* q   = (const float*)d_in[0];
    const float* k   = (const float*)d_in[1];
    const float* v   = (const float*)d_in[2];
    const float* E_w = (const float*)d_in[3];
    const float* E_b = (const float*)d_in[4];
    float* out = (float*)d_out;

    char* ws = (char*)d_ws;
    float*    Kpf = (float*)(ws);                        // 2 MB
    float*    Vpf = (float*)(ws + (2u  << 20));          // 2 MB
    uint16_t* Kbf = (uint16_t*)(ws + (4u  << 20));       // 1 MB
    uint16_t* Vbf = (uint16_t*)(ws + (5u  << 20));       // 1 MB
    uint16_t* Ewb = (uint16_t*)(ws + (6u  << 20));       // 2 MB
    uint16_t* kTb = (uint16_t*)(ws + (8u  << 20));       // 16 MB
    uint16_t* vTb = (uint16_t*)(ws + (24u << 20));       // 16 MB

    hipMemsetAsync(ws, 0, (4u << 20), stream);
    ewcvt<<<512, 256, 0, stream>>>(E_w, Ewb);
    tcvt<<<4096, 256, 0, stream>>>(k, v, kTb, vTb);
    proj_mfma<<<512, 256, 0, stream>>>(Ewb, kTb, vTb, Kpf, Vpf);
    bias_cvt<<<2048, 256, 0, stream>>>(Kpf, Vpf, E_b, Kbf, Vbf);
    attn<<<2048, 256, 0, stream>>>(q, Kbf, Vbf, out);
}

// Round 4
// 131.826 us; speedup vs baseline: 1.7696x; 1.2229x over previous
//
#include <hip/hip_runtime.h>
#include <hip/hip_bf16.h>
#include <stdint.h>

#define B_  32
#define S_  4096
#define D_  64
#define DK_ 256

typedef float f32x4 __attribute__((ext_vector_type(4)));
typedef short s16x8 __attribute__((ext_vector_type(8)));
typedef short s16x4 __attribute__((ext_vector_type(4)));

static __device__ __forceinline__ uint16_t f2bf(float f) {
    union { float f; uint32_t u; } x; x.f = f;
    uint32_t u = x.u;
    u += 0x7FFFu + ((u >> 16) & 1u);   // RNE
    return (uint16_t)(u >> 16);
}

static __device__ __forceinline__ uint32_t pk2(float a, float b) {
    __hip_bfloat162 h = __float22bfloat162_rn(float2{a, b});
    union { __hip_bfloat162 h; uint32_t u; } c; c.h = h;
    return c.u;
}

static __device__ __forceinline__ void gload_lds16(const uint16_t* g, uint16_t* l) {
    __builtin_amdgcn_global_load_lds(
        (const __attribute__((address_space(1))) uint32_t*)g,
        (__attribute__((address_space(3))) uint32_t*)l, 16, 0, 0);
}

// ---------------------------------------------------------------------------
// Pass A1: E_w fp32 -> bf16 (same [DK][S] layout).
// ---------------------------------------------------------------------------
__global__ __launch_bounds__(256) void ewcvt(const float* __restrict__ E_w,
                                             uint16_t* __restrict__ Ewb) {
    const int idx = (blockIdx.x * 256 + threadIdx.x) * 8;
    const float4 f0 = *(const float4*)(E_w + idx);
    const float4 f1 = *(const float4*)(E_w + idx + 4);
    s16x8 o;
    o[0] = (short)f2bf(f0.x); o[1] = (short)f2bf(f0.y);
    o[2] = (short)f2bf(f0.z); o[3] = (short)f2bf(f0.w);
    o[4] = (short)f2bf(f1.x); o[5] = (short)f2bf(f1.y);
    o[6] = (short)f2bf(f1.z); o[7] = (short)f2bf(f1.w);
    *(s16x8*)(Ewb + idx) = o;
}

// ---------------------------------------------------------------------------
// Pass A2: transpose + cvt: x[b][s][d] fp32 -> xT[b][d][s] bf16.
// ---------------------------------------------------------------------------
__global__ __launch_bounds__(256) void tcvt(
        const float* __restrict__ kin, const float* __restrict__ vin,
        uint16_t* __restrict__ kT, uint16_t* __restrict__ vT) {
    const int bid = blockIdx.x;
    const int st  = bid & 63;
    const int b   = (bid >> 6) & 31;
    const int inp = bid >> 11;
    const float* src = (inp ? vin : kin) + ((size_t)b * S_ + st * 64) * D_;
    uint16_t*    dst = (inp ? vT : kT) + (size_t)b * D_ * S_ + st * 64;

    __shared__ __align__(16) uint16_t T[64][72];

    const int t  = threadIdx.x;
    const int ts = t >> 4;
    const int td = t & 15;

    uint16_t tmp[4][4];
    #pragma unroll
    for (int i = 0; i < 4; ++i) {
        const float4 f = *(const float4*)(src + (size_t)(ts*4 + i) * D_ + td*4);
        tmp[i][0] = f2bf(f.x); tmp[i][1] = f2bf(f.y);
        tmp[i][2] = f2bf(f.z); tmp[i][3] = f2bf(f.w);
    }
    #pragma unroll
    for (int j = 0; j < 4; ++j) {
        s16x4 v4;
        v4[0] = (short)tmp[0][j]; v4[1] = (short)tmp[1][j];
        v4[2] = (short)tmp[2][j]; v4[3] = (short)tmp[3][j];
        *(s16x4*)&T[td*4 + j][ts*4] = v4;
    }
    __syncthreads();
    #pragma unroll
    for (int i = 0; i < 2; ++i) {
        const int idx = i * 256 + t;
        const int d = idx >> 3;
        const int c = idx & 7;
        const s16x8 vv = *(const s16x8*)&T[d][c*8];
        *(s16x8*)(dst + (size_t)d * S_ + c*8) = vv;
    }
}

// ---------------------------------------------------------------------------
// Pass B: projection GEMM on MFMA (unchanged from R3).
// ---------------------------------------------------------------------------
__global__ __launch_bounds__(256) void proj_mfma(
        const uint16_t* __restrict__ Ewb,
        const uint16_t* __restrict__ kT, const uint16_t* __restrict__ vT,
        float* __restrict__ Kp, float* __restrict__ Vp) {
    const int bid = blockIdx.x;
    const int ss = bid & 7;
    const int b  = (bid >> 3) & 31;
    const int p  = bid >> 8;
    const uint16_t* xT = (p ? vT : kT) + (size_t)b * D_ * S_;
    float* outp        = (p ? Vp : Kp) + (size_t)b * DK_ * D_;

    __shared__ __align__(16) uint16_t lds[20 * 512];

    const int tid  = threadIdx.x;
    const int w    = tid >> 6;
    const int lane = tid & 63;
    const int l16  = lane & 15;
    const int grp  = lane >> 4;

    const int s0 = ss * 512 + grp * 8;
    const uint16_t* srcA[4];
    #pragma unroll
    for (int i = 0; i < 4; ++i)
        srcA[i] = Ewb + (size_t)((w*4 + i)*16 + l16) * S_ + s0;
    const uint16_t* srcB = xT + (size_t)(w*16 + l16) * S_ + s0;

    f32x4 acc[4][4] = {};

    for (int t = 0; t < 16; ++t) {
        #pragma unroll
        for (int i = 0; i < 4; ++i)
            gload_lds16(srcA[i] + t*32, &lds[(w*4 + i) * 512]);
        gload_lds16(srcB + t*32, &lds[(16 + w) * 512]);
        __syncthreads();

        s16x8 bf[4];
        #pragma unroll
        for (int nt = 0; nt < 4; ++nt)
            bf[nt] = *(const s16x8*)&lds[(16 + nt) * 512 + lane*8];
        #pragma unroll
        for (int m = 0; m < 4; ++m) {
            const s16x8 af = *(const s16x8*)&lds[(w*4 + m) * 512 + lane*8];
            #pragma unroll
            for (int nt = 0; nt < 4; ++nt)
                acc[m][nt] = __builtin_amdgcn_mfma_f32_16x16x32_bf16(af, bf[nt], acc[m][nt], 0, 0, 0);
        }
        __syncthreads();
    }

    #pragma unroll
    for (int m = 0; m < 4; ++m)
        #pragma unroll
        for (int nt = 0; nt < 4; ++nt)
            #pragma unroll
            for (int r = 0; r < 4; ++r)
                atomicAdd(outp + (size_t)(w*64 + m*16 + grp*4 + r) * D_ + nt*16 + l16,
                          acc[m][nt][r]);
}

// ---------------------------------------------------------------------------
// bias + cvt (unchanged)
// ---------------------------------------------------------------------------
__global__ __launch_bounds__(256) void bias_cvt(
        const float* __restrict__ Kp, const float* __restrict__ Vp,
        const float* __restrict__ E_b,
        uint16_t* __restrict__ Kbf, uint16_t* __restrict__ Vbf) {
    const int idx = blockIdx.x * 256 + threadIdx.x;
    const int b  = idx >> 14;
    const int r  = idx & 16383;
    const int kk = r >> 6;
    const int d  = r & 63;
    const float bias = E_b[kk];
    Kbf[idx] = f2bf(Kp[idx] + bias);
    Vbf[((b * 64 + d) << 8) + kk] = f2bf(Vp[idx] + bias);
}

// ---------------------------------------------------------------------------
// attn v2: swapped-operand scores (lane-local P rows), in-register softmax,
// deferred normalization, b64 P writes with XOR swizzle, 32 rows/wave.
// grid = 32 b * 32 tiles = 1024 blocks, 4 waves (128 rows/block).
// ---------------------------------------------------------------------------
__global__ __launch_bounds__(256, 2) void attn(
        const float* __restrict__ q,
        const uint16_t* __restrict__ Kbf, const uint16_t* __restrict__ Vbf,
        float* __restrict__ out) {
    const int wg   = blockIdx.x;
    const int st   = wg & 31;
    const int b    = wg >> 5;
    const int wave = threadIdx.x >> 6;
    const int lane = threadIdx.x & 63;
    const int l16  = lane & 15;
    const int grp  = lane >> 4;
    const int s0   = st * 128 + wave * 32;

    // per-wave 16 KB: raw-exp P, rows = 32 q-rows, cols = 256 kk, XOR-swizzled
    __shared__ __align__(16) uint16_t P_lds[4][32][256];
    char* Pw = (char*)&P_lds[wave][0][0];

    // ---- q B-fragments qb[m][kt]: qrow = s0 + m*16 + l16, d = kt*32+grp*8..+7
    s16x8 qb[2][2];
    #pragma unroll
    for (int m = 0; m < 2; ++m) {
        const float* qp = q + ((size_t)b * S_ + s0 + m*16 + l16) * D_;
        #pragma unroll
        for (int kt = 0; kt < 2; ++kt) {
            const int d0 = kt*32 + grp*8;
            const float4 f0 = *(const float4*)(qp + d0);
            const float4 f1 = *(const float4*)(qp + d0 + 4);
            s16x8 a;
            a[0] = (short)f2bf(f0.x * 0.125f);
            a[1] = (short)f2bf(f0.y * 0.125f);
            a[2] = (short)f2bf(f0.z * 0.125f);
            a[3] = (short)f2bf(f0.w * 0.125f);
            a[4] = (short)f2bf(f1.x * 0.125f);
            a[5] = (short)f2bf(f1.y * 0.125f);
            a[6] = (short)f2bf(f1.z * 0.125f);
            a[7] = (short)f2bf(f1.w * 0.125f);
            qb[m][kt] = a;
        }
    }

    // ---- scores^T: acc[m][nt] holds S[qrow = s0+m*16+l16][kk = nt*16+grp*4+r]
    f32x4 acc[2][16] = {};
    {
        const uint16_t* Kb = Kbf + (size_t)b * DK_ * D_;
        #pragma unroll
        for (int nt = 0; nt < 16; ++nt) {
            #pragma unroll
            for (int kt = 0; kt < 2; ++kt) {
                const s16x8 kf = *(const s16x8*)(Kb + (size_t)(nt*16 + l16) * D_ + kt*32 + grp*8);
                acc[0][nt] = __builtin_amdgcn_mfma_f32_16x16x32_bf16(kf, qb[0][kt], acc[0][nt], 0, 0, 0);
                acc[1][nt] = __builtin_amdgcn_mfma_f32_16x16x32_bf16(kf, qb[1][kt], acc[1][nt], 0, 0, 0);
            }
        }
    }

    // ---- softmax: each lane owns 64 values of ONE q-row per m-tile
    float inv[2];
    #pragma unroll
    for (int m = 0; m < 2; ++m) {
        float mx = acc[m][0][0];
        #pragma unroll
        for (int nt = 0; nt < 16; ++nt)
            #pragma unroll
            for (int r = 0; r < 4; ++r) mx = fmaxf(mx, acc[m][nt][r]);
        mx = fmaxf(mx, __shfl_xor(mx, 16));
        mx = fmaxf(mx, __shfl_xor(mx, 32));
        float sm = 0.f;
        #pragma unroll
        for (int nt = 0; nt < 16; ++nt) {
            #pragma unroll
            for (int r = 0; r < 4; ++r) {
                const float e = __expf(acc[m][nt][r] - mx);
                acc[m][nt][r] = e;
                sm += e;
            }
        }
        sm += __shfl_xor(sm, 16);
        sm += __shfl_xor(sm, 32);
        inv[m] = 1.f / sm;
    }

    // ---- P (raw exp, bf16) -> LDS, ds_write_b64, swizzle byte ^= (row&7)<<4
    #pragma unroll
    for (int m = 0; m < 2; ++m) {
        const int row = m*16 + l16;
        #pragma unroll
        for (int nt = 0; nt < 16; ++nt) {
            uint2 w2;
            w2.x = pk2(acc[m][nt][0], acc[m][nt][1]);
            w2.y = pk2(acc[m][nt][2], acc[m][nt][3]);
            int byte = row*512 + nt*32 + grp*8;
            byte ^= (row & 7) << 4;
            *(uint2*)(Pw + byte) = w2;
        }
    }

    __syncthreads();

    // ---- redistribute inv_sum to PV-output lanes: rows m*16+grp*4+r
    float invs[2][4];
    #pragma unroll
    for (int m = 0; m < 2; ++m)
        #pragma unroll
        for (int r = 0; r < 4; ++r)
            invs[m][r] = __shfl(inv[m], grp*4 + r);

    // ---- PV: out[qrow][d] = sum_kk P * V
    f32x4 o[2][4] = {};
    {
        const uint16_t* Vb = Vbf + (size_t)b * D_ * DK_;
        #pragma unroll
        for (int kt2 = 0; kt2 < 8; ++kt2) {
            s16x8 pa[2];
            #pragma unroll
            for (int m = 0; m < 2; ++m) {
                const int row = m*16 + l16;
                int byte = row*512 + kt2*64 + grp*16;
                byte ^= (row & 7) << 4;
                pa[m] = *(const s16x8*)(Pw + byte);
            }
            #pragma unroll
            for (int nt2 = 0; nt2 < 4; ++nt2) {
                const s16x8 vf = *(const s16x8*)(Vb + (size_t)(nt2*16 + l16) * DK_ + kt2*32 + grp*8);
                o[0][nt2] = __builtin_amdgcn_mfma_f32_16x16x32_bf16(pa[0], vf, o[0][nt2], 0, 0, 0);
                o[1][nt2] = __builtin_amdgcn_mfma_f32_16x16x32_bf16(pa[1], vf, o[1][nt2], 0, 0, 0);
            }
        }
    }

    // ---- epilogue: scale by inv_sum, store
    #pragma unroll
    for (int m = 0; m < 2; ++m)
        #pragma unroll
        for (int nt2 = 0; nt2 < 4; ++nt2)
            #pragma unroll
            for (int r = 0; r < 4; ++r)
                out[((size_t)b * S_ + s0 + m*16 + grp*4 + r) * D_ + nt2*16 + l16] =
                    o[m][nt2][r] * invs[m][r];
}

extern "C" void kernel_launch(void* const* d_in, const int* in_sizes, int n_in,
                              void* d_out, int out_size, void* d_ws, size_t ws_size,
                              hipStream_t stream) {
    const float* q   = (const float*)d_in[0];
    const float* k   = (const float*)d_in[1];
    const float* v   = (const float*)d_in[2];
    const float* E_w = (const float*)d_in[3];
    const float* E_b = (const float*)d_in[4];
    float* out = (float*)d_out;

    char* ws = (char*)d_ws;
    float*    Kpf = (float*)(ws);                        // 2 MB
    float*    Vpf = (float*)(ws + (2u  << 20));          // 2 MB
    uint16_t* Kbf = (uint16_t*)(ws + (4u  << 20));       // 1 MB
    uint16_t* Vbf = (uint16_t*)(ws + (5u  << 20));       // 1 MB
    uint16_t* Ewb = (uint16_t*)(ws + (6u  << 20));       // 2 MB
    uint16_t* kTb = (uint16_t*)(ws + (8u  << 20));       // 16 MB
    uint16_t* vTb = (uint16_t*)(ws + (24u << 20));       // 16 MB

    hipMemsetAsync(ws, 0, (4u << 20), stream);
    ewcvt<<<512, 256, 0, stream>>>(E_w, Ewb);
    tcvt<<<4096, 256, 0, stream>>>(k, v, kTb, vTb);
    proj_mfma<<<512, 256, 0, stream>>>(Ewb, kTb, vTb, Kpf, Vpf);
    bias_cvt<<<2048, 256, 0, stream>>>(Kpf, Vpf, E_b, Kbf, Vbf);
    attn<<<1024, 256, 0, stream>>>(q, Kbf, Vbf, out);
}

// Round 5
// 131.110 us; speedup vs baseline: 1.7793x; 1.0055x over previous
//
#include <hip/hip_runtime.h>
#include <hip/hip_bf16.h>
#include <stdint.h>

#define B_  32
#define S_  4096
#define D_  64
#define DK_ 256

typedef float f32x4 __attribute__((ext_vector_type(4)));
typedef short s16x8 __attribute__((ext_vector_type(8)));
typedef short s16x4 __attribute__((ext_vector_type(4)));
typedef uint32_t u32x4 __attribute__((ext_vector_type(4)));

static __device__ __forceinline__ uint16_t f2bf(float f) {
    union { float f; uint32_t u; } x; x.f = f;
    uint32_t u = x.u;
    u += 0x7FFFu + ((u >> 16) & 1u);   // RNE
    return (uint16_t)(u >> 16);
}

static __device__ __forceinline__ uint32_t pk2(float a, float b) {
    __hip_bfloat162 h = __float22bfloat162_rn(float2{a, b});
    union { __hip_bfloat162 h; uint32_t u; } c; c.h = h;
    return c.u;
}

static __device__ __forceinline__ void gload_lds16(const uint16_t* g, uint16_t* l) {
    __builtin_amdgcn_global_load_lds(
        (const __attribute__((address_space(1))) uint32_t*)g,
        (__attribute__((address_space(3))) uint32_t*)l, 16, 0, 0);
}

// ---------------------------------------------------------------------------
// Pass A1: E_w fp32 -> bf16 (same [DK][S] layout).
// ---------------------------------------------------------------------------
__global__ __launch_bounds__(256) void ewcvt(const float* __restrict__ E_w,
                                             uint16_t* __restrict__ Ewb) {
    const int idx = (blockIdx.x * 256 + threadIdx.x) * 8;
    const float4 f0 = *(const float4*)(E_w + idx);
    const float4 f1 = *(const float4*)(E_w + idx + 4);
    s16x8 o;
    o[0] = (short)f2bf(f0.x); o[1] = (short)f2bf(f0.y);
    o[2] = (short)f2bf(f0.z); o[3] = (short)f2bf(f0.w);
    o[4] = (short)f2bf(f1.x); o[5] = (short)f2bf(f1.y);
    o[6] = (short)f2bf(f1.z); o[7] = (short)f2bf(f1.w);
    *(s16x8*)(Ewb + idx) = o;
}

// ---------------------------------------------------------------------------
// Pass A2: transpose + cvt: x[b][s][d] fp32 -> xT[b][d][s] bf16.
// ---------------------------------------------------------------------------
__global__ __launch_bounds__(256) void tcvt(
        const float* __restrict__ kin, const float* __restrict__ vin,
        uint16_t* __restrict__ kT, uint16_t* __restrict__ vT) {
    const int bid = blockIdx.x;
    const int st  = bid & 63;
    const int b   = (bid >> 6) & 31;
    const int inp = bid >> 11;
    const float* src = (inp ? vin : kin) + ((size_t)b * S_ + st * 64) * D_;
    uint16_t*    dst = (inp ? vT : kT) + (size_t)b * D_ * S_ + st * 64;

    __shared__ __align__(16) uint16_t T[64][72];

    const int t  = threadIdx.x;
    const int ts = t >> 4;
    const int td = t & 15;

    uint16_t tmp[4][4];
    #pragma unroll
    for (int i = 0; i < 4; ++i) {
        const float4 f = *(const float4*)(src + (size_t)(ts*4 + i) * D_ + td*4);
        tmp[i][0] = f2bf(f.x); tmp[i][1] = f2bf(f.y);
        tmp[i][2] = f2bf(f.z); tmp[i][3] = f2bf(f.w);
    }
    #pragma unroll
    for (int j = 0; j < 4; ++j) {
        s16x4 v4;
        v4[0] = (short)tmp[0][j]; v4[1] = (short)tmp[1][j];
        v4[2] = (short)tmp[2][j]; v4[3] = (short)tmp[3][j];
        *(s16x4*)&T[td*4 + j][ts*4] = v4;
    }
    __syncthreads();
    #pragma unroll
    for (int i = 0; i < 2; ++i) {
        const int idx = i * 256 + t;
        const int d = idx >> 3;
        const int c = idx & 7;
        const s16x8 vv = *(const s16x8*)&T[d][c*8];
        *(s16x8*)(dst + (size_t)d * S_ + c*8) = vv;
    }
}

// ---------------------------------------------------------------------------
// Pass B: projection GEMM on MFMA (unchanged).
// ---------------------------------------------------------------------------
__global__ __launch_bounds__(256) void proj_mfma(
        const uint16_t* __restrict__ Ewb,
        const uint16_t* __restrict__ kT, const uint16_t* __restrict__ vT,
        float* __restrict__ Kp, float* __restrict__ Vp) {
    const int bid = blockIdx.x;
    const int ss = bid & 7;
    const int b  = (bid >> 3) & 31;
    const int p  = bid >> 8;
    const uint16_t* xT = (p ? vT : kT) + (size_t)b * D_ * S_;
    float* outp        = (p ? Vp : Kp) + (size_t)b * DK_ * D_;

    __shared__ __align__(16) uint16_t lds[20 * 512];

    const int tid  = threadIdx.x;
    const int w    = tid >> 6;
    const int lane = tid & 63;
    const int l16  = lane & 15;
    const int grp  = lane >> 4;

    const int s0 = ss * 512 + grp * 8;
    const uint16_t* srcA[4];
    #pragma unroll
    for (int i = 0; i < 4; ++i)
        srcA[i] = Ewb + (size_t)((w*4 + i)*16 + l16) * S_ + s0;
    const uint16_t* srcB = xT + (size_t)(w*16 + l16) * S_ + s0;

    f32x4 acc[4][4] = {};

    for (int t = 0; t < 16; ++t) {
        #pragma unroll
        for (int i = 0; i < 4; ++i)
            gload_lds16(srcA[i] + t*32, &lds[(w*4 + i) * 512]);
        gload_lds16(srcB + t*32, &lds[(16 + w) * 512]);
        __syncthreads();

        s16x8 bf[4];
        #pragma unroll
        for (int nt = 0; nt < 4; ++nt)
            bf[nt] = *(const s16x8*)&lds[(16 + nt) * 512 + lane*8];
        #pragma unroll
        for (int m = 0; m < 4; ++m) {
            const s16x8 af = *(const s16x8*)&lds[(w*4 + m) * 512 + lane*8];
            #pragma unroll
            for (int nt = 0; nt < 4; ++nt)
                acc[m][nt] = __builtin_amdgcn_mfma_f32_16x16x32_bf16(af, bf[nt], acc[m][nt], 0, 0, 0);
        }
        __syncthreads();
    }

    #pragma unroll
    for (int m = 0; m < 4; ++m)
        #pragma unroll
        for (int nt = 0; nt < 4; ++nt)
            #pragma unroll
            for (int r = 0; r < 4; ++r)
                atomicAdd(outp + (size_t)(w*64 + m*16 + grp*4 + r) * D_ + nt*16 + l16,
                          acc[m][nt][r]);
}

// ---------------------------------------------------------------------------
// bias + cvt (unchanged)
// ---------------------------------------------------------------------------
__global__ __launch_bounds__(256) void bias_cvt(
        const float* __restrict__ Kp, const float* __restrict__ Vp,
        const float* __restrict__ E_b,
        uint16_t* __restrict__ Kbf, uint16_t* __restrict__ Vbf) {
    const int idx = blockIdx.x * 256 + threadIdx.x;
    const int b  = idx >> 14;
    const int r  = idx & 16383;
    const int kk = r >> 6;
    const int d  = r & 63;
    const float bias = E_b[kk];
    Kbf[idx] = f2bf(Kp[idx] + bias);
    Vbf[((b * 64 + d) << 8) + kk] = f2bf(Vp[idx] + bias);
}

// ---------------------------------------------------------------------------
// attn v4: ZERO LDS. Swapped-operand scores, in-register softmax, deferred
// normalization, and the P D-frag -> A-frag re-layout done as a static
// 4-lane permutation via __shfl (ds_bpermute), no barrier anywhere.
//
// Derivation (verified): pa[m][kt2].u32[c] at lane (g = lane>>4, l = lane&15)
//   = pk[m][2*kt2 + (g>>1)][c&1]  sourced from lane ((2g + (c>>1))&3)*16 + l
// where pk[m][nt][t] = bf16pair(acc[m][nt][2t], acc[m][nt][2t+1]).
// ---------------------------------------------------------------------------
__global__ __launch_bounds__(256, 2) void attn(
        const float* __restrict__ q,
        const uint16_t* __restrict__ Kbf, const uint16_t* __restrict__ Vbf,
        float* __restrict__ out) {
    const int wg   = blockIdx.x;
    const int st   = wg & 31;
    const int b    = wg >> 5;
    const int wave = threadIdx.x >> 6;
    const int lane = threadIdx.x & 63;
    const int l16  = lane & 15;
    const int grp  = lane >> 4;
    const int s0   = st * 128 + wave * 32;

    // ---- q B-fragments qb[m][kt]: qrow = s0 + m*16 + l16, d = kt*32+grp*8..+7
    s16x8 qb[2][2];
    #pragma unroll
    for (int m = 0; m < 2; ++m) {
        const float* qp = q + ((size_t)b * S_ + s0 + m*16 + l16) * D_;
        #pragma unroll
        for (int kt = 0; kt < 2; ++kt) {
            const int d0 = kt*32 + grp*8;
            const float4 f0 = *(const float4*)(qp + d0);
            const float4 f1 = *(const float4*)(qp + d0 + 4);
            s16x8 a;
            a[0] = (short)f2bf(f0.x * 0.125f);
            a[1] = (short)f2bf(f0.y * 0.125f);
            a[2] = (short)f2bf(f0.z * 0.125f);
            a[3] = (short)f2bf(f0.w * 0.125f);
            a[4] = (short)f2bf(f1.x * 0.125f);
            a[5] = (short)f2bf(f1.y * 0.125f);
            a[6] = (short)f2bf(f1.z * 0.125f);
            a[7] = (short)f2bf(f1.w * 0.125f);
            qb[m][kt] = a;
        }
    }

    // ---- scores^T: acc[m][nt][r] = S[qrow=s0+m*16+l16][kk = nt*16+grp*4+r]
    f32x4 acc[2][16] = {};
    {
        const uint16_t* Kb = Kbf + (size_t)b * DK_ * D_;
        #pragma unroll
        for (int nt = 0; nt < 16; ++nt) {
            #pragma unroll
            for (int kt = 0; kt < 2; ++kt) {
                const s16x8 kf = *(const s16x8*)(Kb + (size_t)(nt*16 + l16) * D_ + kt*32 + grp*8);
                acc[0][nt] = __builtin_amdgcn_mfma_f32_16x16x32_bf16(kf, qb[0][kt], acc[0][nt], 0, 0, 0);
                acc[1][nt] = __builtin_amdgcn_mfma_f32_16x16x32_bf16(kf, qb[1][kt], acc[1][nt], 0, 0, 0);
            }
        }
    }

    // ---- softmax: each lane owns 64 of the 256 kk values of ONE row per m
    float inv[2];
    #pragma unroll
    for (int m = 0; m < 2; ++m) {
        float mx = acc[m][0][0];
        #pragma unroll
        for (int nt = 0; nt < 16; ++nt)
            #pragma unroll
            for (int r = 0; r < 4; ++r) mx = fmaxf(mx, acc[m][nt][r]);
        mx = fmaxf(mx, __shfl_xor(mx, 16));
        mx = fmaxf(mx, __shfl_xor(mx, 32));
        float sm = 0.f;
        #pragma unroll
        for (int nt = 0; nt < 16; ++nt) {
            #pragma unroll
            for (int r = 0; r < 4; ++r) {
                const float e = __expf(acc[m][nt][r] - mx);
                acc[m][nt][r] = e;
                sm += e;
            }
        }
        sm += __shfl_xor(sm, 16);
        sm += __shfl_xor(sm, 32);
        inv[m] = 1.f / sm;
    }

    // ---- pack raw-exp P into bf16 pairs (pk lives in regs, acc dies here)
    uint32_t pk[2][16][2];
    #pragma unroll
    for (int m = 0; m < 2; ++m)
        #pragma unroll
        for (int nt = 0; nt < 16; ++nt) {
            pk[m][nt][0] = pk2(acc[m][nt][0], acc[m][nt][1]);
            pk[m][nt][1] = pk2(acc[m][nt][2], acc[m][nt][3]);
        }

    // ---- redistribute inv_sum to PV-output lanes (rows m*16+grp*4+r)
    float invs[2][4];
    #pragma unroll
    for (int m = 0; m < 2; ++m)
        #pragma unroll
        for (int r = 0; r < 4; ++r)
            invs[m][r] = __shfl(inv[m], grp*4 + r);

    // ---- PV with in-register P exchange
    const int sl0 = (((grp << 1) + 0) & 3) * 16 + l16;   // srcLane for c>>1 == 0
    const int sl1 = (((grp << 1) + 1) & 3) * 16 + l16;   // srcLane for c>>1 == 1
    const bool lohalf = (grp < 2);

    f32x4 o[2][4] = {};
    {
        const uint16_t* Vb = Vbf + (size_t)b * D_ * DK_;
        #pragma unroll
        for (int kt2 = 0; kt2 < 8; ++kt2) {
            s16x8 pa[2];
            #pragma unroll
            for (int m = 0; m < 2; ++m) {
                union { u32x4 w; s16x8 h; } u;
                #pragma unroll
                for (int c = 0; c < 4; ++c) {
                    const int t  = c & 1;
                    const int sl = (c >> 1) ? sl1 : sl0;
                    const uint32_t lo = (uint32_t)__shfl((int)pk[m][2*kt2 + 0][t], sl);
                    const uint32_t hi = (uint32_t)__shfl((int)pk[m][2*kt2 + 1][t], sl);
                    u.w[c] = lohalf ? lo : hi;
                }
                pa[m] = u.h;
            }
            #pragma unroll
            for (int nt2 = 0; nt2 < 4; ++nt2) {
                const s16x8 vf = *(const s16x8*)(Vb + (size_t)(nt2*16 + l16) * DK_ + kt2*32 + grp*8);
                o[0][nt2] = __builtin_amdgcn_mfma_f32_16x16x32_bf16(pa[0], vf, o[0][nt2], 0, 0, 0);
                o[1][nt2] = __builtin_amdgcn_mfma_f32_16x16x32_bf16(pa[1], vf, o[1][nt2], 0, 0, 0);
            }
        }
    }

    // ---- epilogue: scale by inv_sum, store
    #pragma unroll
    for (int m = 0; m < 2; ++m)
        #pragma unroll
        for (int nt2 = 0; nt2 < 4; ++nt2)
            #pragma unroll
            for (int r = 0; r < 4; ++r)
                out[((size_t)b * S_ + s0 + m*16 + grp*4 + r) * D_ + nt2*16 + l16] =
                    o[m][nt2][r] * invs[m][r];
}

extern "C" void kernel_launch(void* const* d_in, const int* in_sizes, int n_in,
                              void* d_out, int out_size, void* d_ws, size_t ws_size,
                              hipStream_t stream) {
    const float* q   = (const float*)d_in[0];
    const float* k   = (const float*)d_in[1];
    const float* v   = (const float*)d_in[2];
    const float* E_w = (const float*)d_in[3];
    const float* E_b = (const float*)d_in[4];
    float* out = (float*)d_out;

    char* ws = (char*)d_ws;
    float*    Kpf = (float*)(ws);                        // 2 MB
    float*    Vpf = (float*)(ws + (2u  << 20));          // 2 MB
    uint16_t* Kbf = (uint16_t*)(ws + (4u  << 20));       // 1 MB
    uint16_t* Vbf = (uint16_t*)(ws + (5u  << 20));       // 1 MB
    uint16_t* Ewb = (uint16_t*)(ws + (6u  << 20));       // 2 MB
    uint16_t* kTb = (uint16_t*)(ws + (8u  << 20));       // 16 MB
    uint16_t* vTb = (uint16_t*)(ws + (24u << 20));       // 16 MB

    hipMemsetAsync(ws, 0, (4u << 20), stream);
    ewcvt<<<512, 256, 0, stream>>>(E_w, Ewb);
    tcvt<<<4096, 256, 0, stream>>>(k, v, kTb, vTb);
    proj_mfma<<<512, 256, 0, stream>>>(Ewb, kTb, vTb, Kpf, Vpf);
    bias_cvt<<<2048, 256, 0, stream>>>(Kpf, Vpf, E_b, Kbf, Vbf);
    attn<<<1024, 256, 0, stream>>>(q, Kbf, Vbf, out);
}